// Round 10
// baseline (144.274 us; speedup 1.0000x reference)
//
#include <hip/hip_runtime.h>
#include <hip/hip_bf16.h>
#include <math.h>

#define L_ 8
#define B_ 2
#define N_ 512
#define D_ 1024
#define H_ 8
#define DH_ 64
#define INNER_ 512
#define M_ 16
#define BN_TOK 1024            // B_*N_
#define EPS 1.1920928955078125e-07f
#define SCALE_ 0.125f          // DH^-0.5

typedef __attribute__((ext_vector_type(8))) __bf16 bf16x8;
typedef __attribute__((ext_vector_type(4))) __bf16 bf16x4;
typedef __attribute__((ext_vector_type(4))) float f32x4;

#define BARF() do { __builtin_amdgcn_s_barrier(); __builtin_amdgcn_sched_barrier(0); } while (0)
#define LGKM0() do { asm volatile("s_waitcnt lgkmcnt(0)" ::: "memory"); \
                     __builtin_amdgcn_sched_barrier(0); } while (0)
#define GLL(SRC, DST) __builtin_amdgcn_global_load_lds( \
    (const __attribute__((address_space(1))) void*)(SRC), \
    (__attribute__((address_space(3))) void*)(DST), 16, 0, 0)

// ---------------------------------------------------------------------------
// Consolidated prep (unchanged from R9).
// ---------------------------------------------------------------------------
__device__ void transpose_body(const float* __restrict__ in,
                               __bf16* __restrict__ out, int R, int C,
                               int bx, int by)
{
    __shared__ float tile[32][33];
    const int x = threadIdx.x & 31, y = threadIdx.x >> 5;   // 32 x 8
    #pragma unroll
    for (int r = 0; r < 4; ++r)
        tile[y + r * 8][x] = in[(size_t)(by * 32 + y + r * 8) * C + bx * 32 + x];
    __syncthreads();
    #pragma unroll
    for (int r = 0; r < 4; ++r)
        out[(size_t)(bx * 32 + y + r * 8) * R + by * 32 + x] = (__bf16)tile[x][y + r * 8];
}

__global__ __launch_bounds__(256) void prep_kernel(
    const float* __restrict__ tokens, const float* __restrict__ norm_w,
    const float* __restrict__ w_net, const float* __restrict__ wq,
    const float* __restrict__ wkv, const float* __restrict__ wout,
    const float* __restrict__ wg,
    __bf16* __restrict__ tok_bf, __bf16* __restrict__ tn_bf,
    __bf16* __restrict__ wnet_bf, __bf16* __restrict__ wqt,
    __bf16* __restrict__ wkvt, __bf16* __restrict__ woutt,
    __bf16* __restrict__ wgT)
{
    const int bid = blockIdx.x;
    const int t = threadIdx.x;

    if (bid < 8192) {
        const int wave = t >> 6, lane = t & 63;
        __shared__ float wsum[4];
        const float4 v = ((const float4*)(tokens + (size_t)bid * D_))[t];
        float ss = fmaf(v.x, v.x, fmaf(v.y, v.y, fmaf(v.z, v.z, v.w * v.w)));
        #pragma unroll
        for (int o = 1; o < 64; o <<= 1) ss += __shfl_xor(ss, o);
        if (lane == 0) wsum[wave] = ss;
        __syncthreads();
        const float rsv = rsqrtf((wsum[0] + wsum[1] + wsum[2] + wsum[3]) * (1.f / D_) + EPS);
        const float4 nw = ((const float4*)norm_w)[t];
        bf16x4 tb; tb.x = (__bf16)v.x; tb.y = (__bf16)v.y; tb.z = (__bf16)v.z; tb.w = (__bf16)v.w;
        ((bf16x4*)(tok_bf + (size_t)bid * D_))[t] = tb;
        bf16x4 nb;
        nb.x = (__bf16)(v.x * rsv * nw.x); nb.y = (__bf16)(v.y * rsv * nw.y);
        nb.z = (__bf16)(v.z * rsv * nw.z); nb.w = (__bf16)(v.w * rsv * nw.w);
        ((bf16x4*)(tn_bf + (size_t)bid * D_))[t] = nb;
    } else if (bid < 10240) {
        const int base = (bid - 8192) * 1024 + t;
        #pragma unroll
        for (int j = 0; j < 4; ++j) {
            const int i = base + j * 256;
            float4 v = ((const float4*)w_net)[i];
            bf16x4 o;
            o.x = (__bf16)v.x; o.y = (__bf16)v.y; o.z = (__bf16)v.z; o.w = (__bf16)v.w;
            *(bf16x4*)(wnet_bf + (size_t)i * 4) = o;
        }
    } else if (bid < 12288) {
        const int b2 = bid - 10240;
        if (b2 < 512)        transpose_body(wq, wqt, 1024, 512, b2 & 15, b2 >> 4);
        else if (b2 < 1536)  { const int b3 = b2 - 512;  transpose_body(wkv, wkvt, 1024, 1024, b3 & 31, b3 >> 5); }
        else                 { const int b3 = b2 - 1536; transpose_body(wout, woutt, 512, 1024, b3 & 31, b3 >> 5); }
    } else {
        const int g = (bid - 12288) * 256 + t;
        const int h = g >> 10, d = g & 1023;
        wgT[g] = (h < 8) ? (__bf16)wg[d * 8 + h] : (__bf16)0.f;
    }
}

// ===========================================================================
// CFG0 m201-port: 256x256 tile, BK=64, 8 waves (2m x 4n), wave tile 128x64.
// LDS per buffer per matrix: [2 kh][256 rows][32 cols] (k-half slots, each
// 16 KB, GLL-linear).  Uniform phases:
//   { reads (8 or 4 ds_read_b128) ; stage 1 half-tile (2 GLL) ; barrier ;
//     lgkm0 ; setprio1 ; 16 MFMA ; setprio0 ; barrier }
// Stage schedule per tile t: ph1 A(t+1)kh1, ph2 B(t+1)kh1 (-> buf p^1),
// ph3 A(t+2)kh0, ph4 B(t+2)kh0 (-> buf p, slots freed by ph1/2 drains).
// vmcnt(4) once per tile (proves all but newest 2 halves landed).
// Swizzle: LDS(row,c) = global(row, c ^ ((row>>1)&3)); read chunk
// fq ^ ((fr>>1)&3); source chunk (lane&3)^((lane>>3)&3).  Bit-identical
// accumulation order vs R9.
// ===========================================================================

#define CFG0_DECL()                                                           \
    __shared__ __align__(16) __bf16 As[2][2][256 * 32];  /* 64 KiB */         \
    __shared__ __align__(16) __bf16 Bs[2][2][256 * 32];  /* 64 KiB */

#define CFG0_LANES()                                                          \
    const int schunk = (lane & 3) ^ ((lane >> 3) & 3);                        \
    const int srow = (lane >> 2);                                             \
    const int fsw = (fq ^ ((fr >> 1) & 3)) << 4;

#define STAGE_A(T2, KH, PB) do {                                              \
    _Pragma("unroll")                                                         \
    for (int rd = 0; rd < 2; ++rd)                                            \
        GLL(Ab + (size_t)(rd * 128 + w * 16 + srow) * K + (T2) * 64 + (KH) * 32 + schunk * 8, \
            &As[PB][KH][(rd * 128 + w * 16) * 32]);                           \
} while (0)
#define STAGE_B(T2, KH, PB) do {                                              \
    _Pragma("unroll")                                                         \
    for (int rd = 0; rd < 2; ++rd)                                            \
        GLL(Btb + (size_t)(rd * 128 + w * 16 + srow) * K + (T2) * 64 + (KH) * 32 + schunk * 8, \
            &Bs[PB][KH][(rd * 128 + w * 16) * 32]);                           \
} while (0)
#define RD_A4(DST, MIOFF, KHP) do {                                           \
    _Pragma("unroll")                                                         \
    for (int mi = 0; mi < 4; ++mi)                                            \
        (DST)[mi] = *(const bf16x8*)((KHP) + (((wm * 128 + ((MIOFF) + mi) * 16 + fr) << 6) + fsw)); \
} while (0)
#define RD_B4(DST, KHP) do {                                                  \
    _Pragma("unroll")                                                         \
    for (int nj = 0; nj < 4; ++nj)                                            \
        (DST)[nj] = *(const bf16x8*)((KHP) + (((wn * 64 + nj * 16 + fr) << 6) + fsw)); \
} while (0)
#define MFMA16(AFR, BFR, AOFF) do {                                           \
    _Pragma("unroll")                                                         \
    for (int mi = 0; mi < 4; ++mi)                                            \
        _Pragma("unroll")                                                     \
        for (int nj = 0; nj < 4; ++nj)                                        \
            acc[(AOFF) + mi][nj] = __builtin_amdgcn_mfma_f32_16x16x32_bf16(   \
                (AFR)[mi], (BFR)[nj], acc[(AOFF) + mi][nj], 0, 0, 0);         \
} while (0)

// prologue: tile0 all 4 halves + tile1 k0 halves; vmcnt(4) -> tile0 landed.
#define CFG0_PROLOGUE()                                                       \
    STAGE_A(0, 0, 0); STAGE_B(0, 0, 0);                                       \
    STAGE_A(0, 1, 0); STAGE_B(0, 1, 0);                                       \
    STAGE_A(1, 0, 1); STAGE_B(1, 0, 1);                                       \
    asm volatile("s_waitcnt vmcnt(4)" ::: "memory");                          \
    BARF();

#define CFG0_LOOP(NTv)                                                        \
    for (int t = 0; t < (NTv); ++t) {                                         \
        const int p = t & 1;                                                  \
        const char* A0p = (const char*)&As[p][0][0];                          \
        const char* A1p = (const char*)&As[p][1][0];                          \
        const char* B0p = (const char*)&Bs[p][0][0];                          \
        const char* B1p = (const char*)&Bs[p][1][0];                          \
        bf16x8 al[4], ah[4], bb[4];                                           \
        /* ph1: A-lo k0 + B k0 (8 reads); stage A(t+1) kh1 */                 \
        RD_A4(al, 0, A0p); RD_B4(bb, B0p);                                    \
        if (t + 1 < (NTv)) STAGE_A(t + 1, 1, p ^ 1);                          \
        BARF(); LGKM0();                                                      \
        __builtin_amdgcn_s_setprio(1); MFMA16(al, bb, 0);                     \
        __builtin_amdgcn_s_setprio(0);                                        \
        BARF();                                                               \
        /* ph2: A-hi k0 (4 reads); stage B(t+1) kh1 */                        \
        RD_A4(ah, 4, A0p);                                                    \
        if (t + 1 < (NTv)) STAGE_B(t + 1, 1, p ^ 1);                          \
        BARF(); LGKM0();                                                      \
        __builtin_amdgcn_s_setprio(1); MFMA16(ah, bb, 4);                     \
        __builtin_amdgcn_s_setprio(0);                                        \
        BARF();                                                               \
        /* ph3: A-lo k1 + B k1 (8 reads); stage A(t+2) kh0 (slot drained) */  \
        RD_A4(al, 0, A1p); RD_B4(bb, B1p);                                    \
        if (t + 2 < (NTv)) STAGE_A(t + 2, 0, p);                              \
        BARF(); LGKM0();                                                      \
        __builtin_amdgcn_s_setprio(1); MFMA16(al, bb, 0);                     \
        __builtin_amdgcn_s_setprio(0);                                        \
        BARF();                                                               \
        /* ph4: A-hi k1 (4 reads); stage B(t+2) kh0; per-tile vmcnt */        \
        RD_A4(ah, 4, A1p);                                                    \
        if (t + 2 < (NTv)) STAGE_B(t + 2, 0, p);                              \
        BARF(); LGKM0();                                                      \
        __builtin_amdgcn_s_setprio(1); MFMA16(ah, bb, 4);                     \
        __builtin_amdgcn_s_setprio(0);                                        \
        if (t + 2 < (NTv))      { asm volatile("s_waitcnt vmcnt(4)" ::: "memory"); } \
        else if (t + 1 < (NTv)) { asm volatile("s_waitcnt vmcnt(0)" ::: "memory"); } \
        BARF();                                                               \
    }

// ---------------------------------------------------------------------------
// Fused member linear + q projection + gates.
// ---------------------------------------------------------------------------
__global__ __launch_bounds__(512, 2) void gemm_fused(
    const __bf16* __restrict__ tok, const __bf16* __restrict__ tn,
    const __bf16* __restrict__ wnet, const __bf16* __restrict__ wqt,
    const float* __restrict__ bias, const __bf16* __restrict__ wgT,
    __bf16* __restrict__ out_bf, __bf16* __restrict__ q_bf,
    float* __restrict__ gates_out)
{
    CFG0_DECL();
    constexpr int NT = 16, K = 1024;
    const int tid = threadIdx.x;
    const int w = tid >> 6, lane = tid & 63;
    const int fr = lane & 15, fq = lane >> 4;
    const int bid = blockIdx.x;

    if (bid >= 192) {
        // ---- gates path: wave = 16 rows ----
        const int r0 = ((bid - 192) * 8 + w) * 16;
        const __bf16* arow = tn + (size_t)(r0 + fr) * D_ + fq * 8;
        const __bf16* brow = wgT + (size_t)fr * D_ + fq * 8;
        f32x4 gacc = (f32x4){0.f, 0.f, 0.f, 0.f};
        #pragma unroll 8
        for (int k0 = 0; k0 < D_; k0 += 32) {
            bf16x8 a = *(const bf16x8*)(arow + k0);
            bf16x8 b = *(const bf16x8*)(brow + k0);
            gacc = __builtin_amdgcn_mfma_f32_16x16x32_bf16(a, b, gacc, 0, 0, 0);
        }
        if (fr < 8) {
            #pragma unroll
            for (int r = 0; r < 4; ++r)
                gates_out[(size_t)(r0 + fq * 4 + r) * H_ + fr] = 1.f / (1.f + expf(-gacc[r]));
        }
        return;
    }

    const int wm = w >> 2, wn = w & 3;
    const bool isq = bid >= 128;
    const int b2 = isq ? bid - 128 : bid;
    const int ntx = isq ? 2 : 4;
    const int c = b2 & 7, s = b2 >> 3;
    const int sq = s / ntx;
    const int m0 = (c * 4 + sq) * 256;
    const int n0 = (s - sq * ntx) * 256;
    const __bf16* Ab;
    const __bf16* Btb;
    const float* biasp = nullptr;
    int Ncols;
    if (isq) {
        Ab = tn + (size_t)m0 * K; Btb = wqt + (size_t)n0 * K; Ncols = 512;
    } else {
        Ab = tok + (size_t)m0 * K;
        Btb = wnet + (size_t)(m0 >> 10) * 1024 * K + (size_t)n0 * K;
        Ncols = 1024;
        biasp = bias + (size_t)(m0 >> 10) * 1024;
    }

    CFG0_LANES();
    f32x4 acc[8][4];
    #pragma unroll
    for (int mi = 0; mi < 8; ++mi)
        #pragma unroll
        for (int nj = 0; nj < 4; ++nj)
            acc[mi][nj] = (f32x4){0.f, 0.f, 0.f, 0.f};

    CFG0_PROLOGUE();
    CFG0_LOOP(NT);

    #pragma unroll
    for (int mi = 0; mi < 8; ++mi) {
        const int r0 = m0 + wm * 128 + mi * 16 + fq * 4;
        #pragma unroll
        for (int nj = 0; nj < 4; ++nj) {
            const int col = n0 + wn * 64 + nj * 16 + fr;
            const float badd = (biasp != nullptr) ? biasp[col] : 0.f;
            __bf16* Co = isq ? q_bf : out_bf;
            #pragma unroll
            for (int r = 0; r < 4; ++r)
                Co[(size_t)(r0 + r) * Ncols + col] = (__bf16)(acc[mi][nj][r] + badd);
        }
    }
}

// ---------------------------------------------------------------------------
// kv GEMM (CFG0, row-gather at 8192): kv = [tok; out] @ wkvt^T, 256 blocks.
// ---------------------------------------------------------------------------
__global__ __launch_bounds__(512, 2) void gemm_kv(
    const __bf16* __restrict__ tok, const __bf16* __restrict__ outm,
    const __bf16* __restrict__ wkvt, __bf16* __restrict__ kv_bf)
{
    CFG0_DECL();
    constexpr int NT = 16, K = 1024, Ncols = 1024;
    const int tid = threadIdx.x;
    const int w = tid >> 6, lane = tid & 63;
    const int wm = w >> 2, wn = w & 3;
    const int fr = lane & 15, fq = lane >> 4;
    const int bid = blockIdx.x;
    const int c = bid & 7, s = bid >> 3;
    const int sq = s >> 2;                 // ntx = 4
    const int m0 = (c * 8 + sq) * 256;     // nty/8 = 8
    const int n0 = (s - sq * 4) * 256;
    const __bf16* Ab = (m0 >= 8192) ? (outm + (size_t)(m0 - 8192) * K)
                                    : (tok + (size_t)m0 * K);
    const __bf16* Btb = wkvt + (size_t)n0 * K;

    CFG0_LANES();
    f32x4 acc[8][4];
    #pragma unroll
    for (int mi = 0; mi < 8; ++mi)
        #pragma unroll
        for (int nj = 0; nj < 4; ++nj)
            acc[mi][nj] = (f32x4){0.f, 0.f, 0.f, 0.f};

    CFG0_PROLOGUE();
    CFG0_LOOP(NT);

    #pragma unroll
    for (int mi = 0; mi < 8; ++mi) {
        const int r0 = m0 + wm * 128 + mi * 16 + fq * 4;
        #pragma unroll
        for (int nj = 0; nj < 4; ++nj) {
            const int col = n0 + wn * 64 + nj * 16 + fr;
            #pragma unroll
            for (int r = 0; r < 4; ++r)
                kv_bf[(size_t)(r0 + r) * Ncols + col] = (__bf16)acc[mi][nj][r];
        }
    }
}

#undef STAGE_A
#undef STAGE_B

// ---------------------------------------------------------------------------
// final GEMM (R9 version, unchanged — in-binary control).
// CFG1: BM=256 BN=128, 8 waves (4m x 2n), wave tile 64x64, 256 blocks.
// ---------------------------------------------------------------------------
__global__ __launch_bounds__(512, 2) void gemm_final(
    const __bf16* __restrict__ A,      // og [8192][512]
    const __bf16* __restrict__ Bt,     // woutt [1024][512]
    float* __restrict__ Cf)            // out [8192][1024] f32
{
    __shared__ __align__(16) __bf16 Asf[2][256 * 64];   // 64 KiB
    __shared__ __align__(16) __bf16 Bsf[2][128 * 64];   // 32 KiB
    constexpr int NT = 8, K = 512, Ncols = 1024;
    const int tid = threadIdx.x;
    const int w = tid >> 6, lane = tid & 63;
    const int wm = w >> 1, wn = w & 1;
    const int fr = lane & 15, fq = lane >> 4;
    const int bid = blockIdx.x;
    const int c = bid & 7, s = bid >> 3;
    const int sq = s >> 3;                 // ntx = 8
    const int m0 = (c * 4 + sq) * 256;     // nty/8 = 4
    const int n0 = (s - sq * 8) * 128;
    const __bf16* Ab = A + (size_t)m0 * K;
    const __bf16* Btb = Bt + (size_t)n0 * K;

    const int lrow = lane >> 3;
    const int lchunk = (lane & 7) ^ lrow;
    const int fo0 = ((fq ^ (lane & 7)) << 4);
    const int fo1 = (((4 + fq) ^ (lane & 7)) << 4);

#define F_STAGE_A(T2, PB, HALF) do {                                          \
    _Pragma("unroll")                                                         \
    for (int ld = (HALF) * 2; ld < (HALF) * 2 + 2; ++ld)                      \
        GLL(Ab + (size_t)(w * 32 + ld * 8 + lrow) * K + (T2) * 64 + lchunk * 8, \
            &Asf[PB][(w * 32 + ld * 8) * 64]);                                \
} while (0)
#define F_STAGE_B(T2, PB, HALF)                                               \
    GLL(Btb + (size_t)(w * 16 + (HALF) * 8 + lrow) * K + (T2) * 64 + lchunk * 8, \
        &Bsf[PB][(w * 16 + (HALF) * 8) * 64])
#define F_RD_A(DST, FO) do {                                                  \
    _Pragma("unroll")                                                         \
    for (int mi = 0; mi < 4; ++mi)                                            \
        (DST)[mi] = *(const bf16x8*)(Ap + ((wm * 64 + mi * 16 + fr) << 7) + (FO)); \
} while (0)
#define F_RD_B(DST, FO) do {                                                  \
    _Pragma("unroll")                                                         \
    for (int nj = 0; nj < 4; ++nj)                                            \
        (DST)[nj] = *(const bf16x8*)(Bp + ((wn * 64 + nj * 16 + fr) << 7) + (FO)); \
} while (0)
#define F_MFMA16(AFR, BFR) do {                                               \
    _Pragma("unroll")                                                         \
    for (int mi = 0; mi < 4; ++mi)                                            \
        _Pragma("unroll")                                                     \
        for (int nj = 0; nj < 4; ++nj)                                        \
            acc[mi][nj] = __builtin_amdgcn_mfma_f32_16x16x32_bf16(            \
                (AFR)[mi], (BFR)[nj], acc[mi][nj], 0, 0, 0);                  \
} while (0)

    f32x4 acc[4][4];
    #pragma unroll
    for (int mi = 0; mi < 4; ++mi)
        #pragma unroll
        for (int nj = 0; nj < 4; ++nj)
            acc[mi][nj] = (f32x4){0.f, 0.f, 0.f, 0.f};

    F_STAGE_A(0, 0, 0); F_STAGE_A(0, 0, 1);
    F_STAGE_B(0, 0, 0); F_STAGE_B(0, 0, 1);
    F_STAGE_A(1, 1, 0); F_STAGE_A(1, 1, 1);
    asm volatile("s_waitcnt vmcnt(4)" ::: "memory");
    BARF();

    for (int t = 0; t < NT; ++t) {
        const int p = t & 1;
        const char* Ap = (const char*)&Asf[p][0];
        const char* Bp = (const char*)&Bsf[p][0];
        bf16x8 ak0[4], bk0[4], ak1[4], bk1[4];

        F_RD_A(ak0, fo0); F_RD_B(bk0, fo0);
        if (t + 1 < NT) F_STAGE_B(t + 1, p ^ 1, 0);
        BARF();
        __builtin_amdgcn_s_setprio(1);
        F_MFMA16(ak0, bk0);
        __builtin_amdgcn_s_setprio(0);
        BARF();

        F_RD_A(ak1, fo1); F_RD_B(bk1, fo1);
        if (t + 1 < NT) F_STAGE_B(t + 1, p ^ 1, 1);
        BARF();
        __builtin_amdgcn_s_setprio(1);
        F_MFMA16(ak1, bk1);
        __builtin_amdgcn_s_setprio(0);
        LGKM0();
        BARF();

        if (t + 2 < NT) { F_STAGE_A(t + 2, p, 0); F_STAGE_A(t + 2, p, 1); }
        if (t + 2 < NT) { asm volatile("s_waitcnt vmcnt(4)" ::: "memory"); }
        else            { asm volatile("s_waitcnt vmcnt(0)" ::: "memory"); }
        BARF();
    }

    #pragma unroll
    for (int mi = 0; mi < 4; ++mi) {
        const int r0 = m0 + wm * 64 + mi * 16 + fq * 4;
        #pragma unroll
        for (int nj = 0; nj < 4; ++nj) {
            const int col = n0 + wn * 64 + nj * 16 + fr;
            #pragma unroll
            for (int r = 0; r < 4; ++r)
                Cf[(size_t)(r0 + r) * Ncols + col] = acc[mi][nj][r];
        }
    }
#undef F_STAGE_A
#undef F_STAGE_B
#undef F_RD_A
#undef F_RD_B
#undef F_MFMA16
}

// ---------------------------------------------------------------------------
// Merged-heads attention (unchanged from R9).
// ---------------------------------------------------------------------------
__global__ __launch_bounds__(512) void attn_kernel(
    const __bf16* __restrict__ q,     // [8192, 512]
    const __bf16* __restrict__ kv,    // [16384, 1024]  (k | v)
    const float* __restrict__ gates,  // [8192, 8]
    const float* __restrict__ knw,    // [64]
    __bf16* __restrict__ og)          // [8192, 512]
{
    const int bn = blockIdx.x;        // 0..1023
    const int tid = threadIdx.x;
    const int h = tid >> 6, lane = tid & 63;

    __shared__ __align__(16) __bf16 qs[8][520];
    __shared__ __align__(16) __bf16 kvs[16][1032];
    __shared__ float ssm[8][8][17];   // [h][l][m]
    __shared__ float kn[64];
    __shared__ float gs[64];          // [l*8+h]

    {
        const int l = tid >> 6, c8 = tid & 63;
        *(bf16x8*)&qs[l][c8 * 8] =
            *(const bf16x8*)(q + ((size_t)(l * BN_TOK + bn)) * INNER_ + c8 * 8);
    }
    #pragma unroll
    for (int i = 0; i < 4; ++i) {
        const int g = tid + i * 512;
        const int m = g >> 7, c8 = g & 127;
        *(bf16x8*)&kvs[m][c8 * 8] =
            *(const bf16x8*)(kv + ((size_t)(m * BN_TOK + bn)) * 1024 + c8 * 8);
    }
    if (tid < 64) {
        kn[tid] = knw[tid];
        gs[tid] = gates[((size_t)((tid >> 3) * BN_TOK + bn)) * H_ + (tid & 7)];
    }
    __syncthreads();

    const int m = lane & 15, grp = lane >> 4;

    float s2 = 0.f;
    #pragma unroll
    for (int j = 0; j < 16; ++j) {
        float v = (float)kvs[m][h * DH_ + grp * 16 + j];
        s2 = fmaf(v, v, s2);
    }
    s2 += __shfl_xor(s2, 16);
    s2 += __shfl_xor(s2, 32);
    const float kscale = rsqrtf(s2 * (1.f / DH_) + EPS) * SCALE_;

    const int l0 = grp, l1 = grp + 4;
    float sim0 = 0.f, sim1 = 0.f;
    #pragma unroll
    for (int d = 0; d < DH_; ++d) {
        const float kf = (float)kvs[m][h * DH_ + d] * kn[d];
        sim0 = fmaf((float)qs[l0][h * DH_ + d], kf, sim0);
        sim1 = fmaf((float)qs[l1][h * DH_ + d], kf, sim1);
    }
    sim0 *= kscale; sim1 *= kscale;

    float mx0 = sim0, mx1 = sim1;
    #pragma unroll
    for (int o = 1; o < 16; o <<= 1) {
        mx0 = fmaxf(mx0, __shfl_xor(mx0, o));
        mx1 = fmaxf(mx1, __shfl_xor(mx1, o));
    }
    float e0 = expf(sim0 - mx0), e1 = expf(sim1 - mx1);
    float sm0 = e0, sm1 = e1;
    #pragma unroll
    for (int o = 1; o < 16; o <<= 1) {
        sm0 += __shfl_xor(sm0, o);
        sm1 += __shfl_xor(sm1, o);
    }
    ssm[h][l0][m] = e0 / sm0;
    ssm[h][l1][m] = e1 / sm1;

    float vf[16];
    #pragma unroll
    for (int mm = 0; mm < 16; ++mm)
        vf[mm] = (float)kvs[mm][INNER_ + h * DH_ + lane];
    #pragma unroll
    for (int l = 0; l < 8; ++l) {
        float o = 0.f;
        #pragma unroll
        for (int mm = 0; mm < 16; ++mm) o = fmaf(ssm[h][l][mm], vf[mm], o);
        og[((size_t)(l * BN_TOK + bn)) * INNER_ + h * DH_ + lane] =
            (__bf16)(o * gs[l * 8 + h]);
    }
}

// ---------------------------------------------------------------------------
extern "C" void kernel_launch(void* const* d_in, const int* in_sizes, int n_in,
                              void* d_out, int out_size, void* d_ws, size_t ws_size,
                              hipStream_t stream)
{
    const float* tokens = (const float*)d_in[0];  // [8,2,512,1024]
    const float* w_net  = (const float*)d_in[1];  // [8,1024,1024]
    const float* b_net  = (const float*)d_in[2];  // [8,1024]
    const float* norm_w = (const float*)d_in[3];  // [1024]
    const float* wq     = (const float*)d_in[4];  // [1024,512]
    const float* wkv    = (const float*)d_in[5];  // [1024,1024]
    const float* knw    = (const float*)d_in[6];  // [64]
    const float* wg     = (const float*)d_in[7];  // [1024,8]
    const float* wout   = (const float*)d_in[8];  // [512,1024]
    float* out = (float*)d_out;                   // [8,2,512,1024]

    char* ws = (char*)d_ws;
    __bf16* tok_bf  = (__bf16*)(ws);                         // 16,777,216 B
    __bf16* tn_bf   = (__bf16*)(ws + 16777216);              // 16,777,216
    __bf16* out_bf  = (__bf16*)(ws + 33554432);              // 16,777,216
    __bf16* q_bf    = (__bf16*)(ws + 50331648);              //  8,388,608
    __bf16* kv_bf   = (__bf16*)(ws + 58720256);              // 33,554,432
    __bf16* og_bf   = (__bf16*)(ws + 92274688);              //  8,388,608
    __bf16* wnet_bf = (__bf16*)(ws + 100663296);             // 16,777,216
    __bf16* wqt_bf  = (__bf16*)(ws + 117440512);             //  1,048,576
    __bf16* wkvt_bf = (__bf16*)(ws + 118489088);             //  2,097,152
    __bf16* woutt_bf= (__bf16*)(ws + 120586240);             //  1,048,576
    float*  ws_g    = (float*)(ws + 121667584);              //    262,144
    __bf16* wgT_bf  = (__bf16*)(ws + 121929728);             //     32,768

    // 1. consolidated prep
    prep_kernel<<<12352, 256, 0, stream>>>(tokens, norm_w, w_net, wq, wkv, wout, wg,
                                           tok_bf, tn_bf, wnet_bf, wqt_bf,
                                           wkvt_bf, woutt_bf, wgT_bf);
    // 2. member + q + gates (256 blocks)
    gemm_fused<<<256, 512, 0, stream>>>(tok_bf, tn_bf, wnet_bf, wqt_bf, b_net,
                                        wgT_bf, out_bf, q_bf, ws_g);
    // 3. kv = [tok; out] @ wkv (256 blocks)
    gemm_kv<<<256, 512, 0, stream>>>(tok_bf, out_bf, wkvt_bf, kv_bf);
    // 4. attention + gating
    attn_kernel<<<BN_TOK, 512, 0, stream>>>(q_bf, kv_bf, ws_g, knw, og_bf);
    // 5. pooled = og @ wout -> d_out (f32)
    gemm_final<<<256, 512, 0, stream>>>(og_bf, woutt_bf, out);
}

// Round 11
// 126.415 us; speedup vs baseline: 1.1413x; 1.1413x over previous
//
#include <hip/hip_runtime.h>
#include <hip/hip_bf16.h>
#include <math.h>

#define L_ 8
#define B_ 2
#define N_ 512
#define D_ 1024
#define H_ 8
#define DH_ 64
#define INNER_ 512
#define M_ 16
#define BN_TOK 1024            // B_*N_
#define EPS 1.1920928955078125e-07f
#define SCALE_ 0.125f          // DH^-0.5

typedef __attribute__((ext_vector_type(8))) __bf16 bf16x8;
typedef __attribute__((ext_vector_type(4))) __bf16 bf16x4;
typedef __attribute__((ext_vector_type(4))) float f32x4;

#define BARF() do { __builtin_amdgcn_s_barrier(); __builtin_amdgcn_sched_barrier(0); } while (0)
#define LGKM0() do { asm volatile("s_waitcnt lgkmcnt(0)" ::: "memory"); \
                     __builtin_amdgcn_sched_barrier(0); } while (0)
#define GLL(SRC, DST) __builtin_amdgcn_global_load_lds( \
    (const __attribute__((address_space(1))) void*)(SRC), \
    (__attribute__((address_space(3))) void*)(DST), 16, 0, 0)

// ---------------------------------------------------------------------------
// Consolidated prep: one dispatch.
//   [0,8192):      rs + bf16 converts of tokens/tn (one row each)
//   [8192,10240):  wnet f32->bf16
//   [10240,12288): transposes wq/wkv/wout -> bf16 [N][K]
//   [12288,12352): wgT build (wg [1024][8] f32 -> [16][1024] bf16, rows 8+ =0)
// ---------------------------------------------------------------------------
__device__ void transpose_body(const float* __restrict__ in,
                               __bf16* __restrict__ out, int R, int C,
                               int bx, int by)
{
    __shared__ float tile[32][33];
    const int x = threadIdx.x & 31, y = threadIdx.x >> 5;   // 32 x 8
    #pragma unroll
    for (int r = 0; r < 4; ++r)
        tile[y + r * 8][x] = in[(size_t)(by * 32 + y + r * 8) * C + bx * 32 + x];
    __syncthreads();
    #pragma unroll
    for (int r = 0; r < 4; ++r)
        out[(size_t)(bx * 32 + y + r * 8) * R + by * 32 + x] = (__bf16)tile[x][y + r * 8];
}

__global__ __launch_bounds__(256) void prep_kernel(
    const float* __restrict__ tokens, const float* __restrict__ norm_w,
    const float* __restrict__ w_net, const float* __restrict__ wq,
    const float* __restrict__ wkv, const float* __restrict__ wout,
    const float* __restrict__ wg,
    __bf16* __restrict__ tok_bf, __bf16* __restrict__ tn_bf,
    __bf16* __restrict__ wnet_bf, __bf16* __restrict__ wqt,
    __bf16* __restrict__ wkvt, __bf16* __restrict__ woutt,
    __bf16* __restrict__ wgT)
{
    const int bid = blockIdx.x;
    const int t = threadIdx.x;

    if (bid < 8192) {
        // --- rs + bf16 convert, one (l,b,n) row ---
        const int wave = t >> 6, lane = t & 63;
        __shared__ float wsum[4];
        const float4 v = ((const float4*)(tokens + (size_t)bid * D_))[t];
        float ss = fmaf(v.x, v.x, fmaf(v.y, v.y, fmaf(v.z, v.z, v.w * v.w)));
        #pragma unroll
        for (int o = 1; o < 64; o <<= 1) ss += __shfl_xor(ss, o);
        if (lane == 0) wsum[wave] = ss;
        __syncthreads();
        const float rsv = rsqrtf((wsum[0] + wsum[1] + wsum[2] + wsum[3]) * (1.f / D_) + EPS);
        const float4 nw = ((const float4*)norm_w)[t];
        bf16x4 tb; tb.x = (__bf16)v.x; tb.y = (__bf16)v.y; tb.z = (__bf16)v.z; tb.w = (__bf16)v.w;
        ((bf16x4*)(tok_bf + (size_t)bid * D_))[t] = tb;
        bf16x4 nb;
        nb.x = (__bf16)(v.x * rsv * nw.x); nb.y = (__bf16)(v.y * rsv * nw.y);
        nb.z = (__bf16)(v.z * rsv * nw.z); nb.w = (__bf16)(v.w * rsv * nw.w);
        ((bf16x4*)(tn_bf + (size_t)bid * D_))[t] = nb;
    } else if (bid < 10240) {
        // --- wnet convert ---
        const int base = (bid - 8192) * 1024 + t;
        #pragma unroll
        for (int j = 0; j < 4; ++j) {
            const int i = base + j * 256;
            float4 v = ((const float4*)w_net)[i];
            bf16x4 o;
            o.x = (__bf16)v.x; o.y = (__bf16)v.y; o.z = (__bf16)v.z; o.w = (__bf16)v.w;
            *(bf16x4*)(wnet_bf + (size_t)i * 4) = o;
        }
    } else if (bid < 12288) {
        const int b2 = bid - 10240;
        if (b2 < 512)        transpose_body(wq, wqt, 1024, 512, b2 & 15, b2 >> 4);
        else if (b2 < 1536)  { const int b3 = b2 - 512;  transpose_body(wkv, wkvt, 1024, 1024, b3 & 31, b3 >> 5); }
        else                 { const int b3 = b2 - 1536; transpose_body(wout, woutt, 512, 1024, b3 & 31, b3 >> 5); }
    } else {
        // --- wgT build: 64 blocks x 256 thr = 16384 elems ---
        const int g = (bid - 12288) * 256 + t;
        const int h = g >> 10, d = g & 1023;
        wgT[g] = (h < 8) ? (__bf16)wg[d * 8 + h] : (__bf16)0.f;
    }
}

// ---------------------------------------------------------------------------
// Fused member linear + q projection + gates.  (R9-verified schedule:
// 4 phases, front-loaded reads, single LGKM0 before A-overwrite, counted
// vmcnt(4) per tile.)
//   [0,128):   member  out = tok @ wnet[l]^T + b   (256x256, CFG0)
//   [128,192): q       q = tn @ wqt^T              (256x256, CFG0)
//   [192,256): gates   sigmoid(tn @ wgT^T)  (per-wave MFMA, bf16x8, unroll 8)
// ---------------------------------------------------------------------------
__global__ __launch_bounds__(512, 2) void gemm_fused(
    const __bf16* __restrict__ tok, const __bf16* __restrict__ tn,
    const __bf16* __restrict__ wnet, const __bf16* __restrict__ wqt,
    const float* __restrict__ bias, const __bf16* __restrict__ wgT,
    __bf16* __restrict__ out_bf, __bf16* __restrict__ q_bf,
    float* __restrict__ gates_out)
{
    __shared__ __align__(16) __bf16 As[2][256 * 64];   // 64 KiB
    __shared__ __align__(16) __bf16 Bs[2][256 * 64];   // 64 KiB

    constexpr int NT = 16, K = 1024;
    const int tid = threadIdx.x;
    const int w = tid >> 6, lane = tid & 63;
    const int fr = lane & 15, fq = lane >> 4;
    const int bid = blockIdx.x;

    if (bid >= 192) {
        // ---- gates path: wave = 16 rows ----
        const int r0 = ((bid - 192) * 8 + w) * 16;
        const __bf16* arow = tn + (size_t)(r0 + fr) * D_ + fq * 8;
        const __bf16* brow = wgT + (size_t)fr * D_ + fq * 8;
        f32x4 gacc = (f32x4){0.f, 0.f, 0.f, 0.f};
        #pragma unroll 8
        for (int k0 = 0; k0 < D_; k0 += 32) {
            bf16x8 a = *(const bf16x8*)(arow + k0);
            bf16x8 b = *(const bf16x8*)(brow + k0);
            gacc = __builtin_amdgcn_mfma_f32_16x16x32_bf16(a, b, gacc, 0, 0, 0);
        }
        if (fr < 8) {
            #pragma unroll
            for (int r = 0; r < 4; ++r)
                gates_out[(size_t)(r0 + fq * 4 + r) * H_ + fr] = 1.f / (1.f + expf(-gacc[r]));
        }
        return;
    }

    // ---- member / q (CFG0) ----
    const int wm = w >> 2, wn = w & 3;
    const bool isq = bid >= 128;
    const int b2 = isq ? bid - 128 : bid;
    const int ntx = isq ? 2 : 4;
    const int c = b2 & 7, s = b2 >> 3;
    const int sq = s / ntx;
    const int m0 = (c * 4 + sq) * 256;
    const int n0 = (s - sq * ntx) * 256;
    const __bf16* Ab;
    const __bf16* Btb;
    const float* biasp = nullptr;
    int Ncols;
    if (isq) {
        Ab = tn + (size_t)m0 * K; Btb = wqt + (size_t)n0 * K; Ncols = 512;
    } else {
        Ab = tok + (size_t)m0 * K;
        Btb = wnet + (size_t)(m0 >> 10) * 1024 * K + (size_t)n0 * K;
        Ncols = 1024;
        biasp = bias + (size_t)(m0 >> 10) * 1024;
    }

    const int lrow = lane >> 3;
    const int lchunk = (lane & 7) ^ lrow;
    const int fo0 = ((fq ^ (lane & 7)) << 4);
    const int fo1 = (((4 + fq) ^ (lane & 7)) << 4);

#define STAGE_A(T2, PB, HALF) do {                                            \
    _Pragma("unroll")                                                         \
    for (int ld = (HALF) * 2; ld < (HALF) * 2 + 2; ++ld)                      \
        GLL(Ab + (size_t)(w * 32 + ld * 8 + lrow) * K + (T2) * 64 + lchunk * 8, \
            &As[PB][(w * 32 + ld * 8) * 64]);                                 \
} while (0)
#define STAGE_B(T2, PB, HALF) do {                                            \
    _Pragma("unroll")                                                         \
    for (int ld = (HALF) * 2; ld < (HALF) * 2 + 2; ++ld)                      \
        GLL(Btb + (size_t)(w * 32 + ld * 8 + lrow) * K + (T2) * 64 + lchunk * 8, \
            &Bs[PB][(w * 32 + ld * 8) * 64]);                                 \
} while (0)
#define RD_A(DST, MIOFF, FO) do {                                             \
    _Pragma("unroll")                                                         \
    for (int mi = 0; mi < 4; ++mi)                                            \
        (DST)[mi] = *(const bf16x8*)(Ap + ((wm * 128 + ((MIOFF) + mi) * 16 + fr) << 7) + (FO)); \
} while (0)
#define RD_B(DST, FO) do {                                                    \
    _Pragma("unroll")                                                         \
    for (int nj = 0; nj < 4; ++nj)                                            \
        (DST)[nj] = *(const bf16x8*)(Bp + ((wn * 64 + nj * 16 + fr) << 7) + (FO)); \
} while (0)
#define MFMA16(AFR, BFR, AOFF) do {                                           \
    _Pragma("unroll")                                                         \
    for (int mi = 0; mi < 4; ++mi)                                            \
        _Pragma("unroll")                                                     \
        for (int nj = 0; nj < 4; ++nj)                                        \
            acc[(AOFF) + mi][nj] = __builtin_amdgcn_mfma_f32_16x16x32_bf16(   \
                (AFR)[mi], (BFR)[nj], acc[(AOFF) + mi][nj], 0, 0, 0);         \
} while (0)

    f32x4 acc[8][4];
    #pragma unroll
    for (int mi = 0; mi < 8; ++mi)
        #pragma unroll
        for (int nj = 0; nj < 4; ++nj)
            acc[mi][nj] = (f32x4){0.f, 0.f, 0.f, 0.f};

    STAGE_A(0, 0, 0); STAGE_A(0, 0, 1);
    STAGE_B(0, 0, 0); STAGE_B(0, 0, 1);
    STAGE_A(1, 1, 0); STAGE_A(1, 1, 1);
    asm volatile("s_waitcnt vmcnt(4)" ::: "memory");
    BARF();

    for (int t = 0; t < NT; ++t) {
        const int p = t & 1;
        const char* Ap = (const char*)&As[p][0];
        const char* Bp = (const char*)&Bs[p][0];
        bf16x8 am0k0[4], am1k0[4], bk0[4], am0k1[4], am1k1[4], bk1[4];

        // ph0: k0 frags; stage B(t+1)h0
        RD_A(am0k0, 0, fo0); RD_B(bk0, fo0); RD_A(am1k0, 4, fo0);
        if (t + 1 < NT) STAGE_B(t + 1, p ^ 1, 0);
        BARF();
        __builtin_amdgcn_s_setprio(1);
        MFMA16(am0k0, bk0, 0);
        __builtin_amdgcn_s_setprio(0);
        BARF();

        // ph1: k1 frags; stage B(t+1)h1; MFMA m1k0
        RD_A(am0k1, 0, fo1); RD_B(bk1, fo1); RD_A(am1k1, 4, fo1);
        if (t + 1 < NT) STAGE_B(t + 1, p ^ 1, 1);
        BARF();
        __builtin_amdgcn_s_setprio(1);
        MFMA16(am1k0, bk0, 4);
        __builtin_amdgcn_s_setprio(0);
        LGKM0();                       // all As[p]/Bs[p] reads complete
        BARF();

        // ph2: stage A(t+2)h0 into As[p]; MFMA m0k1
        if (t + 2 < NT) STAGE_A(t + 2, p, 0);
        __builtin_amdgcn_s_setprio(1);
        MFMA16(am0k1, bk1, 0);
        __builtin_amdgcn_s_setprio(0);
        BARF();

        // ph3: stage A(t+2)h1; MFMA m1k1; counted vmcnt; tile-end barrier
        if (t + 2 < NT) STAGE_A(t + 2, p, 1);
        __builtin_amdgcn_s_setprio(1);
        MFMA16(am1k1, bk1, 4);
        __builtin_amdgcn_s_setprio(0);
        if (t + 2 < NT) { asm volatile("s_waitcnt vmcnt(4)" ::: "memory"); }
        else            { asm volatile("s_waitcnt vmcnt(0)" ::: "memory"); }
        BARF();
    }

    #pragma unroll
    for (int mi = 0; mi < 8; ++mi) {
        const int r0 = m0 + wm * 128 + mi * 16 + fq * 4;
        #pragma unroll
        for (int nj = 0; nj < 4; ++nj) {
            const int col = n0 + wn * 64 + nj * 16 + fr;
            const float badd = (biasp != nullptr) ? biasp[col] : 0.f;
            __bf16* Co = isq ? q_bf : out_bf;
            #pragma unroll
            for (int r = 0; r < 4; ++r)
                Co[(size_t)(r0 + r) * Ncols + col] = (__bf16)(acc[mi][nj][r] + badd);
        }
    }
#undef STAGE_A
#undef STAGE_B
#undef RD_A
#undef RD_B
#undef MFMA16
}

// ---------------------------------------------------------------------------
// kv GEMM (CFG0, row-gather at 8192): kv = [tok; out] @ wkvt^T, 256 blocks.
// ---------------------------------------------------------------------------
__global__ __launch_bounds__(512, 2) void gemm_kv(
    const __bf16* __restrict__ tok, const __bf16* __restrict__ outm,
    const __bf16* __restrict__ wkvt, __bf16* __restrict__ kv_bf)
{
    __shared__ __align__(16) __bf16 As[2][256 * 64];
    __shared__ __align__(16) __bf16 Bs[2][256 * 64];
    constexpr int NT = 16, K = 1024, Ncols = 1024;
    const int tid = threadIdx.x;
    const int w = tid >> 6, lane = tid & 63;
    const int wm = w >> 2, wn = w & 3;
    const int fr = lane & 15, fq = lane >> 4;
    const int bid = blockIdx.x;
    const int c = bid & 7, s = bid >> 3;
    const int sq = s >> 2;                 // ntx = 4
    const int m0 = (c * 8 + sq) * 256;     // nty/8 = 8
    const int n0 = (s - sq * 4) * 256;
    const __bf16* Ab = (m0 >= 8192) ? (outm + (size_t)(m0 - 8192) * K)
                                    : (tok + (size_t)m0 * K);
    const __bf16* Btb = wkvt + (size_t)n0 * K;

    const int lrow = lane >> 3;
    const int lchunk = (lane & 7) ^ lrow;
    const int fo0 = ((fq ^ (lane & 7)) << 4);
    const int fo1 = (((4 + fq) ^ (lane & 7)) << 4);

#define STAGE_A(T2, PB, HALF) do {                                            \
    _Pragma("unroll")                                                         \
    for (int ld = (HALF) * 2; ld < (HALF) * 2 + 2; ++ld)                      \
        GLL(Ab + (size_t)(w * 32 + ld * 8 + lrow) * K + (T2) * 64 + lchunk * 8, \
            &As[PB][(w * 32 + ld * 8) * 64]);                                 \
} while (0)
#define STAGE_B(T2, PB, HALF) do {                                            \
    _Pragma("unroll")                                                         \
    for (int ld = (HALF) * 2; ld < (HALF) * 2 + 2; ++ld)                      \
        GLL(Btb + (size_t)(w * 32 + ld * 8 + lrow) * K + (T2) * 64 + lchunk * 8, \
            &Bs[PB][(w * 32 + ld * 8) * 64]);                                 \
} while (0)
#define RD_A(DST, MIOFF, FO) do {                                             \
    _Pragma("unroll")                                                         \
    for (int mi = 0; mi < 4; ++mi)                                            \
        (DST)[mi] = *(const bf16x8*)(Ap + ((wm * 128 + ((MIOFF) + mi) * 16 + fr) << 7) + (FO)); \
} while (0)
#define RD_B(DST, FO) do {                                                    \
    _Pragma("unroll")                                                         \
    for (int nj = 0; nj < 4; ++nj)                                            \
        (DST)[nj] = *(const bf16x8*)(Bp + ((wn * 64 + nj * 16 + fr) << 7) + (FO)); \
} while (0)
#define MFMA16(AFR, BFR, AOFF) do {                                           \
    _Pragma("unroll")                                                         \
    for (int mi = 0; mi < 4; ++mi)                                            \
        _Pragma("unroll")                                                     \
        for (int nj = 0; nj < 4; ++nj)                                        \
            acc[(AOFF) + mi][nj] = __builtin_amdgcn_mfma_f32_16x16x32_bf16(   \
                (AFR)[mi], (BFR)[nj], acc[(AOFF) + mi][nj], 0, 0, 0);         \
} while (0)

    f32x4 acc[8][4];
    #pragma unroll
    for (int mi = 0; mi < 8; ++mi)
        #pragma unroll
        for (int nj = 0; nj < 4; ++nj)
            acc[mi][nj] = (f32x4){0.f, 0.f, 0.f, 0.f};

    STAGE_A(0, 0, 0); STAGE_A(0, 0, 1);
    STAGE_B(0, 0, 0); STAGE_B(0, 0, 1);
    STAGE_A(1, 1, 0); STAGE_A(1, 1, 1);
    asm volatile("s_waitcnt vmcnt(4)" ::: "memory");
    BARF();

    for (int t = 0; t < NT; ++t) {
        const int p = t & 1;
        const char* Ap = (const char*)&As[p][0];
        const char* Bp = (const char*)&Bs[p][0];
        bf16x8 am0k0[4], am1k0[4], bk0[4], am0k1[4], am1k1[4], bk1[4];

        RD_A(am0k0, 0, fo0); RD_B(bk0, fo0); RD_A(am1k0, 4, fo0);
        if (t + 1 < NT) STAGE_B(t + 1, p ^ 1, 0);
        BARF();
        __builtin_amdgcn_s_setprio(1);
        MFMA16(am0k0, bk0, 0);
        __builtin_amdgcn_s_setprio(0);
        BARF();

        RD_A(am0k1, 0, fo1); RD_B(bk1, fo1); RD_A(am1k1, 4, fo1);
        if (t + 1 < NT) STAGE_B(t + 1, p ^ 1, 1);
        BARF();
        __builtin_amdgcn_s_setprio(1);
        MFMA16(am1k0, bk0, 4);
        __builtin_amdgcn_s_setprio(0);
        LGKM0();
        BARF();

        if (t + 2 < NT) STAGE_A(t + 2, p, 0);
        __builtin_amdgcn_s_setprio(1);
        MFMA16(am0k1, bk1, 0);
        __builtin_amdgcn_s_setprio(0);
        BARF();

        if (t + 2 < NT) STAGE_A(t + 2, p, 1);
        __builtin_amdgcn_s_setprio(1);
        MFMA16(am1k1, bk1, 4);
        __builtin_amdgcn_s_setprio(0);
        if (t + 2 < NT) { asm volatile("s_waitcnt vmcnt(4)" ::: "memory"); }
        else            { asm volatile("s_waitcnt vmcnt(0)" ::: "memory"); }
        BARF();
    }

    #pragma unroll
    for (int mi = 0; mi < 8; ++mi) {
        const int r0 = m0 + wm * 128 + mi * 16 + fq * 4;
        #pragma unroll
        for (int nj = 0; nj < 4; ++nj) {
            const int col = n0 + wn * 64 + nj * 16 + fr;
            #pragma unroll
            for (int r = 0; r < 4; ++r)
                kv_bf[(size_t)(r0 + r) * Ncols + col] = (__bf16)acc[mi][nj][r];
        }
    }
#undef STAGE_A
#undef STAGE_B
#undef RD_A
#undef RD_B
#undef MFMA16
}

// ---------------------------------------------------------------------------
// final GEMM, CFG1: BM=256 BN=128, 8 waves (4m x 2n), wave tile 64x64.
// M=8192, N=1024, K=512 -> 256 blocks (full machine).
// ---------------------------------------------------------------------------
__global__ __launch_bounds__(512, 2) void gemm_final(
    const __bf16* __restrict__ A,      // og [8192][512]
    const __bf16* __restrict__ Bt,     // woutt [1024][512]
    float* __restrict__ Cf)            // out [8192][1024] f32
{
    __shared__ __align__(16) __bf16 As[2][256 * 64];   // 64 KiB
    __shared__ __align__(16) __bf16 Bs[2][128 * 64];   // 32 KiB
    constexpr int NT = 8, K = 512, Ncols = 1024;
    const int tid = threadIdx.x;
    const int w = tid >> 6, lane = tid & 63;
    const int wm = w >> 1, wn = w & 1;
    const int fr = lane & 15, fq = lane >> 4;
    const int bid = blockIdx.x;
    const int c = bid & 7, s = bid >> 3;
    const int sq = s >> 3;                 // ntx = 8
    const int m0 = (c * 4 + sq) * 256;     // nty/8 = 4
    const int n0 = (s - sq * 8) * 128;
    const __bf16* Ab = A + (size_t)m0 * K;
    const __bf16* Btb = Bt + (size_t)n0 * K;

    const int lrow = lane >> 3;
    const int lchunk = (lane & 7) ^ lrow;
    const int fo0 = ((fq ^ (lane & 7)) << 4);
    const int fo1 = (((4 + fq) ^ (lane & 7)) << 4);

#define F_STAGE_A(T2, PB, HALF) do {                                          \
    _Pragma("unroll")                                                         \
    for (int ld = (HALF) * 2; ld < (HALF) * 2 + 2; ++ld)                      \
        GLL(Ab + (size_t)(w * 32 + ld * 8 + lrow) * K + (T2) * 64 + lchunk * 8, \
            &As[PB][(w * 32 + ld * 8) * 64]);                                 \
} while (0)
#define F_STAGE_B(T2, PB, HALF)                                               \
    GLL(Btb + (size_t)(w * 16 + (HALF) * 8 + lrow) * K + (T2) * 64 + lchunk * 8, \
        &Bs[PB][(w * 16 + (HALF) * 8) * 64])
#define F_RD_A(DST, FO) do {                                                  \
    _Pragma("unroll")                                                         \
    for (int mi = 0; mi < 4; ++mi)                                            \
        (DST)[mi] = *(const bf16x8*)(Ap + ((wm * 64 + mi * 16 + fr) << 7) + (FO)); \
} while (0)
#define F_RD_B(DST, FO) do {                                                  \
    _Pragma("unroll")                                                         \
    for (int nj = 0; nj < 4; ++nj)                                            \
        (DST)[nj] = *(const bf16x8*)(Bp + ((wn * 64 + nj * 16 + fr) << 7) + (FO)); \
} while (0)
#define F_MFMA16(AFR, BFR) do {                                               \
    _Pragma("unroll")                                                         \
    for (int mi = 0; mi < 4; ++mi)                                            \
        _Pragma("unroll")                                                     \
        for (int nj = 0; nj < 4; ++nj)                                        \
            acc[mi][nj] = __builtin_amdgcn_mfma_f32_16x16x32_bf16(            \
                (AFR)[mi], (BFR)[nj], acc[mi][nj], 0, 0, 0);                  \
} while (0)

    f32x4 acc[4][4];
    #pragma unroll
    for (int mi = 0; mi < 4; ++mi)
        #pragma unroll
        for (int nj = 0; nj < 4; ++nj)
            acc[mi][nj] = (f32x4){0.f, 0.f, 0.f, 0.f};

    F_STAGE_A(0, 0, 0); F_STAGE_A(0, 0, 1);
    F_STAGE_B(0, 0, 0); F_STAGE_B(0, 0, 1);
    F_STAGE_A(1, 1, 0); F_STAGE_A(1, 1, 1);
    asm volatile("s_waitcnt vmcnt(4)" ::: "memory");
    BARF();

    for (int t = 0; t < NT; ++t) {
        const int p = t & 1;
        const char* Ap = (const char*)&As[p][0];
        const char* Bp = (const char*)&Bs[p][0];
        bf16x8 ak0[4], bk0[4], ak1[4], bk1[4];

        F_RD_A(ak0, fo0); F_RD_B(bk0, fo0);
        if (t + 1 < NT) F_STAGE_B(t + 1, p ^ 1, 0);
        BARF();
        __builtin_amdgcn_s_setprio(1);
        F_MFMA16(ak0, bk0);
        __builtin_amdgcn_s_setprio(0);
        BARF();

        F_RD_A(ak1, fo1); F_RD_B(bk1, fo1);
        if (t + 1 < NT) F_STAGE_B(t + 1, p ^ 1, 1);
        BARF();
        __builtin_amdgcn_s_setprio(1);
        F_MFMA16(ak1, bk1);
        __builtin_amdgcn_s_setprio(0);
        LGKM0();
        BARF();

        if (t + 2 < NT) { F_STAGE_A(t + 2, p, 0); F_STAGE_A(t + 2, p, 1); }
        if (t + 2 < NT) { asm volatile("s_waitcnt vmcnt(4)" ::: "memory"); }
        else            { asm volatile("s_waitcnt vmcnt(0)" ::: "memory"); }
        BARF();
    }

    #pragma unroll
    for (int mi = 0; mi < 4; ++mi) {
        const int r0 = m0 + wm * 64 + mi * 16 + fq * 4;
        #pragma unroll
        for (int nj = 0; nj < 4; ++nj) {
            const int col = n0 + wn * 64 + nj * 16 + fr;
            #pragma unroll
            for (int r = 0; r < 4; ++r)
                Cf[(size_t)(r0 + r) * Ncols + col] = acc[mi][nj][r];
        }
    }
#undef F_STAGE_A
#undef F_STAGE_B
#undef F_RD_A
#undef F_RD_B
#undef F_MFMA16
}

// ---------------------------------------------------------------------------
// Merged-heads attention: one 512-thread block per (b,n) site; wave = head.
// ---------------------------------------------------------------------------
__global__ __launch_bounds__(512) void attn_kernel(
    const __bf16* __restrict__ q,     // [8192, 512]
    const __bf16* __restrict__ kv,    // [16384, 1024]  (k | v)
    const float* __restrict__ gates,  // [8192, 8]
    const float* __restrict__ knw,    // [64]
    __bf16* __restrict__ og)          // [8192, 512]
{
    const int bn = blockIdx.x;        // 0..1023
    const int tid = threadIdx.x;
    const int h = tid >> 6, lane = tid & 63;

    __shared__ __align__(16) __bf16 qs[8][520];
    __shared__ __align__(16) __bf16 kvs[16][1032];
    __shared__ float ssm[8][8][17];   // [h][l][m]
    __shared__ float kn[64];
    __shared__ float gs[64];          // [l*8+h]

    {
        const int l = tid >> 6, c8 = tid & 63;
        *(bf16x8*)&qs[l][c8 * 8] =
            *(const bf16x8*)(q + ((size_t)(l * BN_TOK + bn)) * INNER_ + c8 * 8);
    }
    #pragma unroll
    for (int i = 0; i < 4; ++i) {
        const int g = tid + i * 512;
        const int m = g >> 7, c8 = g & 127;
        *(bf16x8*)&kvs[m][c8 * 8] =
            *(const bf16x8*)(kv + ((size_t)(m * BN_TOK + bn)) * 1024 + c8 * 8);
    }
    if (tid < 64) {
        kn[tid] = knw[tid];
        gs[tid] = gates[((size_t)((tid >> 3) * BN_TOK + bn)) * H_ + (tid & 7)];
    }
    __syncthreads();

    const int m = lane & 15, grp = lane >> 4;

    float s2 = 0.f;
    #pragma unroll
    for (int j = 0; j < 16; ++j) {
        float v = (float)kvs[m][h * DH_ + grp * 16 + j];
        s2 = fmaf(v, v, s2);
    }
    s2 += __shfl_xor(s2, 16);
    s2 += __shfl_xor(s2, 32);
    const float kscale = rsqrtf(s2 * (1.f / DH_) + EPS) * SCALE_;

    const int l0 = grp, l1 = grp + 4;
    float sim0 = 0.f, sim1 = 0.f;
    #pragma unroll
    for (int d = 0; d < DH_; ++d) {
        const float kf = (float)kvs[m][h * DH_ + d] * kn[d];
        sim0 = fmaf((float)qs[l0][h * DH_ + d], kf, sim0);
        sim1 = fmaf((float)qs[l1][h * DH_ + d], kf, sim1);
    }
    sim0 *= kscale; sim1 *= kscale;

    float mx0 = sim0, mx1 = sim1;
    #pragma unroll
    for (int o = 1; o < 16; o <<= 1) {
        mx0 = fmaxf(mx0, __shfl_xor(mx0, o));
        mx1 = fmaxf(mx1, __shfl_xor(mx1, o));
    }
    float e0 = expf(sim0 - mx0), e1 = expf(sim1 - mx1);
    float sm0 = e0, sm1 = e1;
    #pragma unroll
    for (int o = 1; o < 16; o <<= 1) {
        sm0 += __shfl_xor(sm0, o);
        sm1 += __shfl_xor(sm1, o);
    }
    ssm[h][l0][m] = e0 / sm0;
    ssm[h][l1][m] = e1 / sm1;

    float vf[16];
    #pragma unroll
    for (int mm = 0; mm < 16; ++mm)
        vf[mm] = (float)kvs[mm][INNER_ + h * DH_ + lane];
    #pragma unroll
    for (int l = 0; l < 8; ++l) {
        float o = 0.f;
        #pragma unroll
        for (int mm = 0; mm < 16; ++mm) o = fmaf(ssm[h][l][mm], vf[mm], o);
        og[((size_t)(l * BN_TOK + bn)) * INNER_ + h * DH_ + lane] =
            (__bf16)(o * gs[l * 8 + h]);
    }
}

// ---------------------------------------------------------------------------
extern "C" void kernel_launch(void* const* d_in, const int* in_sizes, int n_in,
                              void* d_out, int out_size, void* d_ws, size_t ws_size,
                              hipStream_t stream)
{
    const float* tokens = (const float*)d_in[0];  // [8,2,512,1024]
    const float* w_net  = (const float*)d_in[1];  // [8,1024,1024]
    const float* b_net  = (const float*)d_in[2];  // [8,1024]
    const float* norm_w = (const float*)d_in[3];  // [1024]
    const float* wq     = (const float*)d_in[4];  // [1024,512]
    const float* wkv    = (const float*)d_in[5];  // [1024,1024]
    const float* knw    = (const float*)d_in[6];  // [64]
    const float* wg     = (const float*)d_in[7];  // [1024,8]
    const float* wout   = (const float*)d_in[8];  // [512,1024]
    float* out = (float*)d_out;                   // [8,2,512,1024]

    char* ws = (char*)d_ws;
    __bf16* tok_bf  = (__bf16*)(ws);                         // 16,777,216 B
    __bf16* tn_bf   = (__bf16*)(ws + 16777216);              // 16,777,216
    __bf16* out_bf  = (__bf16*)(ws + 33554432);              // 16,777,216
    __bf16* q_bf    = (__bf16*)(ws + 50331648);              //  8,388,608
    __bf16* kv_bf   = (__bf16*)(ws + 58720256);              // 33,554,432
    __bf16* og_bf   = (__bf16*)(ws + 92274688);              //  8,388,608
    __bf16* wnet_bf = (__bf16*)(ws + 100663296);             // 16,777,216
    __bf16* wqt_bf  = (__bf16*)(ws + 117440512);             //  1,048,576
    __bf16* wkvt_bf = (__bf16*)(ws + 118489088);             //  2,097,152
    __bf16* woutt_bf= (__bf16*)(ws + 120586240);             //  1,048,576
    float*  ws_g    = (float*)(ws + 121667584);              //    262,144
    __bf16* wgT_bf  = (__bf16*)(ws + 121929728);             //     32,768

    // 1. consolidated prep (rs + weight conversions + wgT)
    prep_kernel<<<12352, 256, 0, stream>>>(tokens, norm_w, w_net, wq, wkv, wout, wg,
                                           tok_bf, tn_bf, wnet_bf, wqt_bf,
                                           wkvt_bf, woutt_bf, wgT_bf);
    // 2. member + q + gates (256 blocks, full machine)
    gemm_fused<<<256, 512, 0, stream>>>(tok_bf, tn_bf, wnet_bf, wqt_bf, b_net,
                                        wgT_bf, out_bf, q_bf, ws_g);
    // 3. kv = [tok; out] @ wkv (256 blocks)
    gemm_kv<<<256, 512, 0, stream>>>(tok_bf, out_bf, wkvt_bf, kv_bf);
    // 4. attention + gating
    attn_kernel<<<BN_TOK, 512, 0, stream>>>(q_bf, kv_bf, ws_g, knw, og_bf);
    // 5. pooled = og @ wout -> d_out (f32, 256 blocks CFG1)
    gemm_final<<<256, 512, 0, stream>>>(og_bf, woutt_bf, out);
}